// Round 4
// baseline (2410.571 us; speedup 1.0000x reference)
//
#include <hip/hip_runtime.h>
#include <hip/hip_bf16.h>

// Attention-augmented LSTM encoder. B=2048, T=128, N=128, H=256.
// softmax shift-invariance -> attention time-invariant; w_h/w_c/b_attn dead.
//
// Round 4: fully block-local recurrence. 256 blocks x 1024 threads (16 waves,
// 4/SIMD). Each wave holds its 16 gate-cols x 4 gates of the packed weight
// matrix as 48 persistent MFMA B-fragments (192 VGPRs) -> whole 768KB weight
// matrix lives in the CU register file. Each block owns M=8 batch rows:
// h ping-pongs in LDS (one __syncthreads/step), c in registers, wx staged
// through LDS with a one-step prefetch. NO inter-block sync of any kind
// (rounds 1/3 died on cross-block L3 latency; round 2 on weight restream).
// MFMA A rows 8..15 are zero padding; garbage there only affects discarded
// C rows (D row r depends only on A row r).

#define B_ 2048
#define T_ 128
#define N_ 128
#define H_ 256
#define M_ 8
#define NBLK (B_ / M_)   // 256 blocks, 1/CU

typedef float f32x4 __attribute__((ext_vector_type(4)));
typedef short bf16x8 __attribute__((ext_vector_type(8)));
typedef unsigned short u16;
typedef u16 u16x4 __attribute__((ext_vector_type(4)));

__device__ __forceinline__ u16 f2bf(float f) {
  unsigned int u = __float_as_uint(f);
  u += 0x7fffu + ((u >> 16) & 1u);   // RNE
  return (u16)(u >> 16);
}
__device__ __forceinline__ float sigm(float x) { return 1.f / (1.f + __expf(-x)); }
__device__ __forceinline__ float tanh_(float x) {
  float e = __expf(2.f * x);
  return 1.f - 2.f / (e + 1.f);
}

// ---------------------------------------------------------------- kernel 1
__global__ __launch_bounds__(128) void attn_wx_kernel(
    const float* __restrict__ x, const float* __restrict__ w_attn,
    float* __restrict__ out0) {
  const int b = blockIdx.x;
  const int n = threadIdx.x;
  const float* xb = x + (size_t)b * (T_ * N_);
  __shared__ float red[N_];
  float xv[T_];
  float p = 0.f;
#pragma unroll
  for (int t = 0; t < T_; ++t) {
    xv[t] = xb[t * N_ + n];
    p += xv[t] * w_attn[2 * H_ + t];
  }
  red[n] = p;
  __syncthreads();
  float m = red[0];
  for (int i = 1; i < N_; ++i) m = fmaxf(m, red[i]);
  float e = __expf(p - m);
  __syncthreads();
  red[n] = e;
  __syncthreads();
  float s = 0.f;
  for (int i = 0; i < N_; ++i) s += red[i];
  const float a = e / s;
  float* ob = out0 + (size_t)b * (T_ * N_);
#pragma unroll
  for (int t = 0; t < T_; ++t) ob[t * N_ + n] = a * xv[t];
}

// ------------------------------------------------------- weight prepack
// frag(g16=0..15, q=0..3, kc=0..11) at ((g16*4+q)*12+kc)*512; elem j of lane l
// = W[q*256+g16*16+(l&15)][kc*32+((l>>4)<<3)+j], W = [w_ih | w_hh], K=384.
__global__ __launch_bounds__(256) void prepack_kernel(
    const float* __restrict__ w_ih, const float* __restrict__ w_hh,
    u16* __restrict__ wpk) {
  const int idx = blockIdx.x * 256 + threadIdx.x;  // 393216
  const int j = idx & 7;
  const int l = (idx >> 3) & 63;
  const int rest = idx >> 9;
  const int kc = rest % 12;
  const int wq = rest / 12;
  const int q = wq & 3;
  const int g16 = wq >> 2;
  const int grow = q * H_ + g16 * 16 + (l & 15);
  const int k = kc * 32 + ((l >> 4) << 3) + j;
  const float v = (k < N_) ? w_ih[(size_t)grow * N_ + k]
                           : w_hh[(size_t)grow * H_ + (k - N_)];
  wpk[idx] = f2bf(v);
}

// ---------------------------------------------------------------- kernel 2
__global__ __launch_bounds__(1024, 4) void lstm_kernel(
    const float* __restrict__ wx,      // out0 f32 [B][T][N]
    const u16* __restrict__ wpk,       // packed bf16 weights (768 KB)
    const float* __restrict__ b_ih, const float* __restrict__ b_hh,
    float* __restrict__ out1) {        // f32 [B][T][H]
  __shared__ u16 hsh[2][16][264];      // h ping-pong, rows 8..15 stay zero
  __shared__ u16 xsh[2][16][136];      // wx bf16 staging, rows 8..15 zero
  const int tid  = threadIdx.x;
  const int w    = tid >> 6;           // wave 0..15 -> 16-col group
  const int lane = tid & 63;
  const int l15  = lane & 15;
  const int koff = (lane >> 4) << 3;
  const int rb   = blockIdx.x * M_;
  const int hcol = w * 16 + l15;

  // persistent weights: 48 frags = 192 VGPRs per lane
  bf16x8 wfrag[4][12];
  {
    const u16* wp = wpk + (size_t)(w * 48) * 512 + (size_t)lane * 8;
#pragma unroll
    for (int q = 0; q < 4; ++q)
#pragma unroll
      for (int kc = 0; kc < 12; ++kc)
        wfrag[q][kc] = *(const bf16x8*)(wp + (size_t)(q * 12 + kc) * 512);
  }
  float bias[4];
#pragma unroll
  for (int q = 0; q < 4; ++q)
    bias[q] = b_ih[q * H_ + hcol] + b_hh[q * H_ + hcol];

  // zero LDS (both buffers; pad rows stay zero forever)
  {
    u16* p0 = &hsh[0][0][0];
    for (int i = tid; i < 2 * 16 * 264; i += 1024) p0[i] = 0;
    u16* p1 = &xsh[0][0][0];
    for (int i = tid; i < 2 * 16 * 136; i += 1024) p1[i] = 0;
  }
  __syncthreads();

  // stage wx for t=0 (rows 0..7 only)
  const int srow = tid >> 5, scol = (tid & 31) * 4;
  if (tid < 256) {
    f32x4 v = *(const f32x4*)(wx + (size_t)(rb + srow) * (T_ * N_) + scol);
    u16x4 o;
    o[0] = f2bf(v[0]); o[1] = f2bf(v[1]); o[2] = f2bf(v[2]); o[3] = f2bf(v[3]);
    *(u16x4*)&xsh[0][srow][scol] = o;
  }
  __syncthreads();

  float creg[4] = {0.f, 0.f, 0.f, 0.f};

  for (int t = 0; t < T_; ++t) {
    // ---- prefetch next step's wx (latency hidden under MFMA+cell)
    f32x4 pf;
    const bool do_pf = (tid < 256) & (t + 1 < T_);
    if (do_pf)
      pf = *(const f32x4*)(wx + (size_t)(rb + srow) * (T_ * N_)
                              + (size_t)(t + 1) * N_ + scol);

    // ---- A fragments from LDS
    bf16x8 ax[4], ah[8];
#pragma unroll
    for (int kc = 0; kc < 4; ++kc)
      ax[kc] = *(const bf16x8*)&xsh[t & 1][l15][kc * 32 + koff];
#pragma unroll
    for (int kc = 0; kc < 8; ++kc)
      ah[kc] = *(const bf16x8*)&hsh[t & 1][l15][kc * 32 + koff];

    // ---- MFMA: gates[16x64-of-1024] = [wx | h] @ W^T, bias pre-seeded
    f32x4 acc[4];
#pragma unroll
    for (int q = 0; q < 4; ++q)
      acc[q] = (f32x4){bias[q], bias[q], bias[q], bias[q]};
#pragma unroll
    for (int kc = 0; kc < 4; ++kc)
#pragma unroll
      for (int q = 0; q < 4; ++q)
        acc[q] = __builtin_amdgcn_mfma_f32_16x16x32_bf16(ax[kc], wfrag[q][kc], acc[q], 0, 0, 0);
#pragma unroll
    for (int kc = 0; kc < 8; ++kc)
#pragma unroll
      for (int q = 0; q < 4; ++q)
        acc[q] = __builtin_amdgcn_mfma_f32_16x16x32_bf16(ah[kc], wfrag[q][4 + kc], acc[q], 0, 0, 0);

    // ---- LSTM cell: rows 0..7 live in lanes 0..31
    if (lane < 32) {
#pragma unroll
      for (int rr = 0; rr < 4; ++rr) {
        const float gi = acc[0][rr];
        const float gf = acc[1][rr];
        const float gg = acc[2][rr];
        const float go = acc[3][rr];
        const float c = sigm(gf) * creg[rr] + sigm(gi) * tanh_(gg);
        creg[rr] = c;
        const float h = sigm(go) * tanh_(c);
        const int row = ((lane >> 4) << 2) + rr;
        out1[(size_t)(rb + row) * (T_ * H_) + (size_t)t * H_ + hcol] = h;
        hsh[(t + 1) & 1][row][hcol] = f2bf(h);
      }
    }

    // ---- commit prefetched wx into the other buffer
    if (do_pf) {
      u16x4 o;
      o[0] = f2bf(pf[0]); o[1] = f2bf(pf[1]); o[2] = f2bf(pf[2]); o[3] = f2bf(pf[3]);
      *(u16x4*)&xsh[(t + 1) & 1][srow][scol] = o;
    }
    __syncthreads();   // h[nxt] + wx[nxt] complete before next step reads
  }
}

// ---------------------------------------------------------------- launch
extern "C" void kernel_launch(void* const* d_in, const int* in_sizes, int n_in,
                              void* d_out, int out_size, void* d_ws, size_t ws_size,
                              hipStream_t stream) {
  const float* x      = (const float*)d_in[0];
  const float* w_ih   = (const float*)d_in[1];
  const float* w_hh   = (const float*)d_in[2];
  const float* b_ih   = (const float*)d_in[3];
  const float* b_hh   = (const float*)d_in[4];
  const float* w_attn = (const float*)d_in[5];
  // d_in[6] (b_attn) provably unused (softmax shift invariance).

  float* out0 = (float*)d_out;                   // [B][T][N] input_weighted
  float* out1 = out0 + (size_t)B_ * T_ * N_;     // [B][T][H] input_encoded
  u16* wpk    = (u16*)d_ws;                      // 768 KB packed weights

  prepack_kernel<<<dim3(1536), dim3(256), 0, stream>>>(w_ih, w_hh, wpk);
  attn_wx_kernel<<<dim3(B_), dim3(N_), 0, stream>>>(x, w_attn, out0);
  lstm_kernel<<<dim3(NBLK), dim3(1024), 0, stream>>>(out0, wpk, b_ih, b_hh, out1);
}

// Round 5
// 989.573 us; speedup vs baseline: 2.4360x; 2.4360x over previous
//
#include <hip/hip_runtime.h>
#include <hip/hip_bf16.h>

// Attention-augmented LSTM encoder. B=2048, T=128, N=128, H=256.
// softmax shift-invariance -> attention time-invariant; w_h/w_c/b_attn dead.
//
// Round 5: weight-stationary, 4-way column split, minimal exchange chain.
// HW facts driving the design: VGPR pool = 512 slots/SIMD (so (256,1) blocks
// get up to 512 regs/wave; 1024-thr blocks cap at 128 -> round-4 spill);
// full 768KB weight matrix can never be register-resident on one CU.
// 256 blocks x 256 thr: block = rowgroup(32 rows) x colgroup(64 h-cols,
// all 4 gates). Each wave: 16 h-cols x 4 gates = 48 B-frags = 192 VGPRs.
// Per step: own h-cols via LDS; 3 partner slices (32x64 bf16) via L3 with
// relaxed sc0sc1 loads; per-WAVE relaxed flag stores (no RMW, no sleep,
// flag goes out BEFORE the end-of-step barrier); wx prefetched 1 step ahead.

#define B_ 2048
#define T_ 128
#define N_ 128
#define H_ 256
#define RG_ 64   // rowgroups of 32 rows

typedef float f32x4 __attribute__((ext_vector_type(4)));
typedef short bf16x8 __attribute__((ext_vector_type(8)));
typedef unsigned short u16;

__device__ __forceinline__ u16 f2bf(float f) {
  unsigned int u = __float_as_uint(f);
  u += 0x7fffu + ((u >> 16) & 1u);   // RNE
  return (u16)(u >> 16);
}
__device__ __forceinline__ float sigm(float x) { return 1.f / (1.f + __expf(-x)); }
__device__ __forceinline__ float tanh_(float x) {
  float e = __expf(2.f * x);
  return 1.f - 2.f / (e + 1.f);
}

// device-coherent (L3) 16B load / 2B store, relaxed (no cache maintenance)
__device__ __forceinline__ bf16x8 ld16_dev(const u16* p) {
  bf16x8 v;
  asm volatile("global_load_dwordx4 %0, %1, off sc0 sc1" : "=v"(v) : "v"(p));
  return v;
}
__device__ __forceinline__ void st2_dev(u16* p, unsigned int v) {
  asm volatile("global_store_short %0, %1, off sc0 sc1" :: "v"(p), "v"(v));
}

// ---------------------------------------------------------------- kernel 1
__global__ __launch_bounds__(128) void attn_wx_kernel(
    const float* __restrict__ x, const float* __restrict__ w_attn,
    float* __restrict__ out0) {
  const int b = blockIdx.x;
  const int n = threadIdx.x;
  const float* xb = x + (size_t)b * (T_ * N_);
  __shared__ float red[N_];
  float xv[T_];
  float p = 0.f;
#pragma unroll
  for (int t = 0; t < T_; ++t) {
    xv[t] = xb[t * N_ + n];
    p += xv[t] * w_attn[2 * H_ + t];
  }
  red[n] = p;
  __syncthreads();
  float m = red[0];
  for (int i = 1; i < N_; ++i) m = fmaxf(m, red[i]);
  float e = __expf(p - m);
  __syncthreads();
  red[n] = e;
  __syncthreads();
  float s = 0.f;
  for (int i = 0; i < N_; ++i) s += red[i];
  const float a = e / s;
  float* ob = out0 + (size_t)b * (T_ * N_);
#pragma unroll
  for (int t = 0; t < T_; ++t) ob[t * N_ + n] = a * xv[t];
}

// ------------------------------------------------------- weight prepack
// frag(g16=0..15, q=0..3, kc=0..11) at ((g16*4+q)*12+kc)*512; elem j of lane l
// = W[q*256+g16*16+(l&15)][kc*32+((l>>4)<<3)+j], W = [w_ih | w_hh], K=384.
__global__ __launch_bounds__(256) void prepack_kernel(
    const float* __restrict__ w_ih, const float* __restrict__ w_hh,
    u16* __restrict__ wpk) {
  const int idx = blockIdx.x * 256 + threadIdx.x;  // 393216
  const int j = idx & 7;
  const int l = (idx >> 3) & 63;
  const int rest = idx >> 9;
  const int kc = rest % 12;
  const int wq = rest / 12;
  const int q = wq & 3;
  const int g16 = wq >> 2;
  const int grow = q * H_ + g16 * 16 + (l & 15);
  const int k = kc * 32 + ((l >> 4) << 3) + j;
  const float v = (k < N_) ? w_ih[(size_t)grow * N_ + k]
                           : w_hh[(size_t)grow * H_ + (k - N_)];
  wpk[idx] = f2bf(v);
}

// ---------------------------------------------------------------- kernel 2
__global__ __launch_bounds__(256, 1) void lstm_kernel(
    const float* __restrict__ wx,      // out0 f32 [B][T][N]
    const u16* __restrict__ wpk,
    const float* __restrict__ b_ih, const float* __restrict__ b_hh,
    float* __restrict__ out1,          // f32 [B][T][H]
    u16* __restrict__ hx,              // [2][RG][4][32][64] bf16
    int* __restrict__ flags) {         // [RG][4 cg][4 wave]
  __shared__ u16 hsh[2][32][72];       // own 64 h-cols, ping-pong, padded
  const int bid = blockIdx.x;
  const int rg = bid >> 2, cg = bid & 3;
  const int rb = rg * 32;
  const int tid  = threadIdx.x;
  const int w    = tid >> 6;           // wave 0..3
  const int lane = tid & 63;
  const int l15  = lane & 15;
  const int koff = (lane >> 4) << 3;
  const int g16  = cg * 4 + w;
  const int hcol = cg * 64 + w * 16 + l15;

  // persistent weights: 48 frags = 192 VGPRs
  bf16x8 wfrag[4][12];
  {
    const u16* wp = wpk + (size_t)(g16 * 48) * 512 + (size_t)lane * 8;
#pragma unroll
    for (int q = 0; q < 4; ++q)
#pragma unroll
      for (int kc = 0; kc < 12; ++kc)
        wfrag[q][kc] = *(const bf16x8*)(wp + (size_t)(q * 12 + kc) * 512);
  }
  float bias[4];
#pragma unroll
  for (int q = 0; q < 4; ++q)
    bias[q] = b_ih[q * H_ + hcol] + b_hh[q * H_ + hcol];
  float creg[2][4] = {};

  int* fl = &flags[rg * 16];
  int* myflag = &flags[(rg * 4 + cg) * 4 + w];

  // prefetch wx for t=0
  f32x4 pf[2][4][2];
#pragma unroll
  for (int mt = 0; mt < 2; ++mt)
#pragma unroll
    for (int kc = 0; kc < 4; ++kc) {
      const float* p = wx + (size_t)(rb + mt * 16 + l15) * (T_ * N_)
                          + kc * 32 + koff;
      pf[mt][kc][0] = *(const f32x4*)p;
      pf[mt][kc][1] = *(const f32x4*)(p + 4);
    }

  for (int t = 0; t < T_; ++t) {
    f32x4 acc[2][4];
#pragma unroll
    for (int mt = 0; mt < 2; ++mt)
#pragma unroll
      for (int q = 0; q < 4; ++q)
        acc[mt][q] = (f32x4){bias[q], bias[q], bias[q], bias[q]};

    // ---- wx part: convert prefetched regs, MFMA (off the exchange path)
#pragma unroll
    for (int kc = 0; kc < 4; ++kc)
#pragma unroll
      for (int mt = 0; mt < 2; ++mt) {
        f32x4 x0 = pf[mt][kc][0], x1 = pf[mt][kc][1];
        bf16x8 a;
        a[0] = (short)f2bf(x0[0]); a[1] = (short)f2bf(x0[1]);
        a[2] = (short)f2bf(x0[2]); a[3] = (short)f2bf(x0[3]);
        a[4] = (short)f2bf(x1[0]); a[5] = (short)f2bf(x1[1]);
        a[6] = (short)f2bf(x1[2]); a[7] = (short)f2bf(x1[3]);
#pragma unroll
        for (int q = 0; q < 4; ++q)
          acc[mt][q] = __builtin_amdgcn_mfma_f32_16x16x32_bf16(a, wfrag[q][kc], acc[mt][q], 0, 0, 0);
      }
    // ---- issue wx prefetch for t+1 (latency hidden under poll/MFMA/cell)
    if (t + 1 < T_) {
#pragma unroll
      for (int mt = 0; mt < 2; ++mt)
#pragma unroll
        for (int kc = 0; kc < 4; ++kc) {
          const float* p = wx + (size_t)(rb + mt * 16 + l15) * (T_ * N_)
                              + (size_t)(t + 1) * N_ + kc * 32 + koff;
          pf[mt][kc][0] = *(const f32x4*)p;
          pf[mt][kc][1] = *(const f32x4*)(p + 4);
        }
    }

    // ---- h part
    if (t > 0) {
      // all-lane spin on all 16 flags of this rowgroup (own 4 are already >= t)
      int mn;
      do {
        mn = 0x7fffffff;
#pragma unroll
        for (int i = 0; i < 16; ++i) {
          int v = __hip_atomic_load(&fl[i], __ATOMIC_RELAXED, __HIP_MEMORY_SCOPE_AGENT);
          mn = min(mn, v);
        }
      } while (mn < t);
      __builtin_amdgcn_sched_barrier(0);

      const u16* hxr = hx + (size_t)(t & 1) * (RG_ * 4 * 32 * 64)
                          + (size_t)rg * (4 * 32 * 64);
      bf16x8 ah[2][8];
#pragma unroll
      for (int mt = 0; mt < 2; ++mt)
#pragma unroll
        for (int kc2 = 0; kc2 < 8; ++kc2) {
          const int pc = kc2 >> 1, kcl = kc2 & 1;
          if (pc == cg)   // block-uniform branch
            ah[mt][kc2] = *(const bf16x8*)&hsh[t & 1][mt * 16 + l15][kcl * 32 + koff];
          else
            ah[mt][kc2] = ld16_dev(hxr + (size_t)pc * 2048
                                   + (mt * 16 + l15) * 64 + kcl * 32 + koff);
        }
      asm volatile("s_waitcnt vmcnt(0)" ::: "memory");
      __builtin_amdgcn_sched_barrier(0);
#pragma unroll
      for (int kc2 = 0; kc2 < 8; ++kc2)
#pragma unroll
        for (int q = 0; q < 4; ++q)
#pragma unroll
          for (int mt = 0; mt < 2; ++mt)
            acc[mt][q] = __builtin_amdgcn_mfma_f32_16x16x32_bf16(ah[mt][kc2], wfrag[q][4 + kc2], acc[mt][q], 0, 0, 0);
    }

    // ---- LSTM cell (in-register; lane owns hcol in all 4 gate quadrants)
    u16* hxw = hx + (size_t)((t + 1) & 1) * (RG_ * 4 * 32 * 64)
                  + ((size_t)rg * 4 + cg) * (32 * 64);
#pragma unroll
    for (int mt = 0; mt < 2; ++mt)
#pragma unroll
      for (int rr = 0; rr < 4; ++rr) {
        const float gi = acc[mt][0][rr];
        const float gf = acc[mt][1][rr];
        const float gg = acc[mt][2][rr];
        const float go = acc[mt][3][rr];
        const float c = sigm(gf) * creg[mt][rr] + sigm(gi) * tanh_(gg);
        creg[mt][rr] = c;
        const float h = sigm(go) * tanh_(c);
        const int row = mt * 16 + ((lane >> 4) << 2) + rr;
        out1[(size_t)(rb + row) * (T_ * H_) + (size_t)t * H_ + hcol] = h;
        const u16 hb = f2bf(h);
        hsh[(t + 1) & 1][row][w * 16 + l15] = hb;
        st2_dev(hxw + row * 64 + w * 16 + l15, (unsigned int)hb);
      }
    asm volatile("s_waitcnt vmcnt(0)" ::: "memory");   // h at coherence point
    if (lane == 0)
      __hip_atomic_store(myflag, t + 1, __ATOMIC_RELAXED, __HIP_MEMORY_SCOPE_AGENT);
    __syncthreads();   // hsh[nxt] ready for all waves next step
  }
}

// ---------------------------------------------------------------- launch
extern "C" void kernel_launch(void* const* d_in, const int* in_sizes, int n_in,
                              void* d_out, int out_size, void* d_ws, size_t ws_size,
                              hipStream_t stream) {
  const float* x      = (const float*)d_in[0];
  const float* w_ih   = (const float*)d_in[1];
  const float* w_hh   = (const float*)d_in[2];
  const float* b_ih   = (const float*)d_in[3];
  const float* b_hh   = (const float*)d_in[4];
  const float* w_attn = (const float*)d_in[5];
  // d_in[6] (b_attn) provably unused (softmax shift invariance).

  float* out0 = (float*)d_out;                   // [B][T][N] input_weighted
  float* out1 = out0 + (size_t)B_ * T_ * N_;     // [B][T][H] input_encoded

  int* flags = (int*)d_ws;                                   // 4 KB
  u16* wpk   = (u16*)((char*)d_ws + 16384);                  // 768 KB
  u16* hx    = (u16*)((char*)d_ws + 16384 + 786432);         // 2 MB

  hipMemsetAsync(d_ws, 0, RG_ * 4 * 4 * sizeof(int), stream);
  prepack_kernel<<<dim3(1536), dim3(256), 0, stream>>>(w_ih, w_hh, wpk);
  attn_wx_kernel<<<dim3(B_), dim3(N_), 0, stream>>>(x, w_attn, out0);
  lstm_kernel<<<dim3(256), dim3(256), 0, stream>>>(out0, wpk, b_ih, b_hh,
                                                   out1, hx, flags);
}

// Round 6
// 961.209 us; speedup vs baseline: 2.5079x; 1.0295x over previous
//
#include <hip/hip_runtime.h>
#include <hip/hip_bf16.h>

// Attention-augmented LSTM encoder. B=2048, T=128, N=128, H=256.
// softmax shift-invariance -> attention time-invariant; w_h/w_c/b_attn dead.
//
// Round 6: round-5 topology (256 blocks = 32-row x 64-hcol tiles, weights
// persistent in VGPRs, relaxed sc0sc1 L3 exchange) with a minimal-transaction
// exchange protocol:
//  - producer repacks h through LDS into consumer-ready MFMA A-fragments;
//    ONE contiguous 1KB dwordx4 sc0sc1 store per wave (was 8 scattered 2B
//    stores per thread -> 512 tiny L3 writes per wave).
//  - consumer loads 12 partner fragments as coalesced 1KB dwordx4 loads.
//  - 16 u8 flags packed in one 16B line -> ONE dwordx4 per poll iteration
//    (was 16 separate dword loads), plain byte stores, no atomics/RMW.

#define B_ 2048
#define T_ 128
#define N_ 128
#define H_ 256
#define RG_ 64   // rowgroups of 32 rows

typedef float f32x4 __attribute__((ext_vector_type(4)));
typedef short bf16x8 __attribute__((ext_vector_type(8)));
typedef unsigned short u16;
typedef unsigned int u32;
typedef u32 u32x4 __attribute__((ext_vector_type(4)));

__device__ __forceinline__ u16 f2bf(float f) {
  unsigned int u = __float_as_uint(f);
  u += 0x7fffu + ((u >> 16) & 1u);   // RNE
  return (u16)(u >> 16);
}
__device__ __forceinline__ float sigm(float x) { return 1.f / (1.f + __expf(-x)); }
__device__ __forceinline__ float tanh_(float x) {
  float e = __expf(2.f * x);
  return 1.f - 2.f / (e + 1.f);
}

// device-coherent (L3) ops, relaxed (no cache-maintenance instructions)
__device__ __forceinline__ bf16x8 ld16_dev(const u16* p) {
  bf16x8 v;
  asm volatile("global_load_dwordx4 %0, %1, off sc0 sc1" : "=v"(v) : "v"(p));
  return v;
}
__device__ __forceinline__ void st16_dev(u16* p, bf16x8 v) {
  asm volatile("global_store_dwordx4 %0, %1, off sc0 sc1" :: "v"(p), "v"(v) : "memory");
}
__device__ __forceinline__ void st1_dev(unsigned char* p, u32 v) {
  asm volatile("global_store_byte %0, %1, off sc0 sc1" :: "v"(p), "v"(v) : "memory");
}
__device__ __forceinline__ u32x4 ld_flags(const unsigned char* p) {
  u32x4 f;
  asm volatile("global_load_dwordx4 %0, %1, off sc0 sc1\n\ts_waitcnt vmcnt(0)"
               : "=v"(f) : "v"(p) : "memory");
  return f;
}

// ---------------------------------------------------------------- kernel 1
__global__ __launch_bounds__(128) void attn_wx_kernel(
    const float* __restrict__ x, const float* __restrict__ w_attn,
    float* __restrict__ out0) {
  const int b = blockIdx.x;
  const int n = threadIdx.x;
  const float* xb = x + (size_t)b * (T_ * N_);
  __shared__ float red[N_];
  float xv[T_];
  float p = 0.f;
#pragma unroll
  for (int t = 0; t < T_; ++t) {
    xv[t] = xb[t * N_ + n];
    p += xv[t] * w_attn[2 * H_ + t];
  }
  red[n] = p;
  __syncthreads();
  float m = red[0];
  for (int i = 1; i < N_; ++i) m = fmaxf(m, red[i]);
  float e = __expf(p - m);
  __syncthreads();
  red[n] = e;
  __syncthreads();
  float s = 0.f;
  for (int i = 0; i < N_; ++i) s += red[i];
  const float a = e / s;
  float* ob = out0 + (size_t)b * (T_ * N_);
#pragma unroll
  for (int t = 0; t < T_; ++t) ob[t * N_ + n] = a * xv[t];
}

// ------------------------------------------------------- weight prepack
// frag(g16=0..15, q=0..3, kc=0..11) at ((g16*4+q)*12+kc)*512; elem j of lane l
// = W[q*256+g16*16+(l&15)][kc*32+((l>>4)<<3)+j], W = [w_ih | w_hh], K=384.
__global__ __launch_bounds__(256) void prepack_kernel(
    const float* __restrict__ w_ih, const float* __restrict__ w_hh,
    u16* __restrict__ wpk) {
  const int idx = blockIdx.x * 256 + threadIdx.x;  // 393216
  const int j = idx & 7;
  const int l = (idx >> 3) & 63;
  const int rest = idx >> 9;
  const int kc = rest % 12;
  const int wq = rest / 12;
  const int q = wq & 3;
  const int g16 = wq >> 2;
  const int grow = q * H_ + g16 * 16 + (l & 15);
  const int k = kc * 32 + ((l >> 4) << 3) + j;
  const float v = (k < N_) ? w_ih[(size_t)grow * N_ + k]
                           : w_hh[(size_t)grow * H_ + (k - N_)];
  wpk[idx] = f2bf(v);
}

// ---------------------------------------------------------------- kernel 2
__global__ __launch_bounds__(256, 1) void lstm_kernel(
    const float* __restrict__ wx,      // out0 f32 [B][T][N]
    const u16* __restrict__ wpk,
    const float* __restrict__ b_ih, const float* __restrict__ b_hh,
    float* __restrict__ out1,          // f32 [B][T][H]
    u16* __restrict__ hx,              // [2][RG][4 pc][4 frag][512 u16]
    unsigned char* __restrict__ flags) { // [RG][16 u8] one line per rowgroup
  __shared__ u16 hsh[2][32][72];       // own 64 h-cols, ping-pong, padded
  const int bid = blockIdx.x;
  const int rg = bid >> 2, cg = bid & 3;
  const int rb = rg * 32;
  const int tid  = threadIdx.x;
  const int w    = tid >> 6;           // wave 0..3
  const int lane = tid & 63;
  const int l15  = lane & 15;
  const int koff = (lane >> 4) << 3;
  const int g16  = cg * 4 + w;
  const int hcol = cg * 64 + w * 16 + l15;

  // persistent weights: 48 frags = 192 VGPRs
  bf16x8 wfrag[4][12];
  {
    const u16* wp = wpk + (size_t)(g16 * 48) * 512 + (size_t)lane * 8;
#pragma unroll
    for (int q = 0; q < 4; ++q)
#pragma unroll
      for (int kc = 0; kc < 12; ++kc)
        wfrag[q][kc] = *(const bf16x8*)(wp + (size_t)(q * 12 + kc) * 512);
  }
  float bias[4];
#pragma unroll
  for (int q = 0; q < 4; ++q)
    bias[q] = b_ih[q * H_ + hcol] + b_hh[q * H_ + hcol];
  float creg[2][4] = {};

  unsigned char* flrow  = flags + rg * 16;
  unsigned char* myflag = flrow + cg * 4 + w;
  const int mtf = w >> 1, kclf = w & 1;   // fragment this wave exports

  // prefetch wx for t=0
  f32x4 pf[2][4][2];
#pragma unroll
  for (int mt = 0; mt < 2; ++mt)
#pragma unroll
    for (int kc = 0; kc < 4; ++kc) {
      const float* p = wx + (size_t)(rb + mt * 16 + l15) * (T_ * N_)
                          + kc * 32 + koff;
      pf[mt][kc][0] = *(const f32x4*)p;
      pf[mt][kc][1] = *(const f32x4*)(p + 4);
    }

  for (int t = 0; t < T_; ++t) {
    f32x4 acc[2][4];
#pragma unroll
    for (int mt = 0; mt < 2; ++mt)
#pragma unroll
      for (int q = 0; q < 4; ++q)
        acc[mt][q] = (f32x4){bias[q], bias[q], bias[q], bias[q]};

    // ---- wx part: convert prefetched regs, MFMA (off the exchange path)
#pragma unroll
    for (int kc = 0; kc < 4; ++kc)
#pragma unroll
      for (int mt = 0; mt < 2; ++mt) {
        f32x4 x0 = pf[mt][kc][0], x1 = pf[mt][kc][1];
        bf16x8 a;
        a[0] = (short)f2bf(x0[0]); a[1] = (short)f2bf(x0[1]);
        a[2] = (short)f2bf(x0[2]); a[3] = (short)f2bf(x0[3]);
        a[4] = (short)f2bf(x1[0]); a[5] = (short)f2bf(x1[1]);
        a[6] = (short)f2bf(x1[2]); a[7] = (short)f2bf(x1[3]);
#pragma unroll
        for (int q = 0; q < 4; ++q)
          acc[mt][q] = __builtin_amdgcn_mfma_f32_16x16x32_bf16(a, wfrag[q][kc], acc[mt][q], 0, 0, 0);
      }
    // ---- issue wx prefetch for t+1 (drained by first poll iteration)
    if (t + 1 < T_) {
#pragma unroll
      for (int mt = 0; mt < 2; ++mt)
#pragma unroll
        for (int kc = 0; kc < 4; ++kc) {
          const float* p = wx + (size_t)(rb + mt * 16 + l15) * (T_ * N_)
                              + (size_t)(t + 1) * N_ + kc * 32 + koff;
          pf[mt][kc][0] = *(const f32x4*)p;
          pf[mt][kc][1] = *(const f32x4*)(p + 4);
        }
    }

    // ---- h part
    if (t > 0) {
      // spin: one 16B flag-line load per iteration; need all 16 u8 >= t
      while (true) {
        u32x4 f = ld_flags(flrow);
        int ok = 1;
#pragma unroll
        for (int i = 0; i < 4; ++i) {
          u32 v = f[i];
          ok &= ((v & 255u) >= (u32)t) & (((v >> 8) & 255u) >= (u32)t) &
                (((v >> 16) & 255u) >= (u32)t) & (((v >> 24) & 255u) >= (u32)t);
        }
        if (ok) break;
      }
      __builtin_amdgcn_sched_barrier(0);

      const u16* hxr = hx + ((size_t)(t & 1) * RG_ + rg) * (4 * 4 * 512);
      bf16x8 ah[2][8];
#pragma unroll
      for (int mt = 0; mt < 2; ++mt)
#pragma unroll
        for (int kc2 = 0; kc2 < 8; ++kc2) {
          const int pc = kc2 >> 1, kcl = kc2 & 1;
          if (pc == cg)   // block-uniform branch
            ah[mt][kc2] = *(const bf16x8*)&hsh[t & 1][mt * 16 + l15][kcl * 32 + koff];
          else            // coalesced 1KB fragment load, lane*16B
            ah[mt][kc2] = ld16_dev(hxr + ((size_t)pc * 4 + (mt * 2 + kcl)) * 512
                                       + (size_t)lane * 8);
        }
      asm volatile("s_waitcnt vmcnt(0)" ::: "memory");
      __builtin_amdgcn_sched_barrier(0);
#pragma unroll
      for (int kc2 = 0; kc2 < 8; ++kc2)
#pragma unroll
        for (int q = 0; q < 4; ++q)
#pragma unroll
          for (int mt = 0; mt < 2; ++mt)
            acc[mt][q] = __builtin_amdgcn_mfma_f32_16x16x32_bf16(ah[mt][kc2], wfrag[q][4 + kc2], acc[mt][q], 0, 0, 0);
    }

    // ---- LSTM cell (in-register) -> hsh[nxt] + out1
    const int nxt = (t + 1) & 1;
#pragma unroll
    for (int mt = 0; mt < 2; ++mt)
#pragma unroll
      for (int rr = 0; rr < 4; ++rr) {
        const float gi = acc[mt][0][rr];
        const float gf = acc[mt][1][rr];
        const float gg = acc[mt][2][rr];
        const float go = acc[mt][3][rr];
        const float c = sigm(gf) * creg[mt][rr] + sigm(gi) * tanh_(gg);
        creg[mt][rr] = c;
        const float h = sigm(go) * tanh_(c);
        const int row = mt * 16 + ((lane >> 4) << 2) + rr;
        out1[(size_t)(rb + row) * (T_ * H_) + (size_t)t * H_ + hcol] = h;
        hsh[nxt][row][w * 16 + l15] = f2bf(h);
      }
    __syncthreads();   // hsh[nxt] complete across all 4 waves

    // ---- fragment export: ONE contiguous 1KB store per wave, then flag
    {
      bf16x8 fv = *(const bf16x8*)&hsh[nxt][mtf * 16 + l15][kclf * 32 + koff];
      u16* dst = hx + (((size_t)nxt * RG_ + rg) * 4 + cg) * (4 * 512)
                    + (size_t)w * 512 + (size_t)lane * 8;
      st16_dev(dst, fv);
      asm volatile("s_waitcnt vmcnt(0)" ::: "memory");  // frag (+out1) at L3
      if (lane == 0) st1_dev(myflag, (u32)(t + 1));
    }
  }
}

// ---------------------------------------------------------------- launch
extern "C" void kernel_launch(void* const* d_in, const int* in_sizes, int n_in,
                              void* d_out, int out_size, void* d_ws, size_t ws_size,
                              hipStream_t stream) {
  const float* x      = (const float*)d_in[0];
  const float* w_ih   = (const float*)d_in[1];
  const float* w_hh   = (const float*)d_in[2];
  const float* b_ih   = (const float*)d_in[3];
  const float* b_hh   = (const float*)d_in[4];
  const float* w_attn = (const float*)d_in[5];
  // d_in[6] (b_attn) provably unused (softmax shift invariance).

  float* out0 = (float*)d_out;                   // [B][T][N] input_weighted
  float* out1 = out0 + (size_t)B_ * T_ * N_;     // [B][T][H] input_encoded

  unsigned char* flags = (unsigned char*)d_ws;               // 1 KB
  u16* wpk = (u16*)((char*)d_ws + 16384);                    // 768 KB
  u16* hx  = (u16*)((char*)d_ws + 16384 + 786432);           // 2 MB

  hipMemsetAsync(d_ws, 0, RG_ * 16, stream);
  prepack_kernel<<<dim3(1536), dim3(256), 0, stream>>>(w_ih, w_hh, wpk);
  attn_wx_kernel<<<dim3(B_), dim3(N_), 0, stream>>>(x, w_attn, out0);
  lstm_kernel<<<dim3(256), dim3(256), 0, stream>>>(out0, wpk, b_ih, b_hh,
                                                   out1, hx, flags);
}